// Round 3
// baseline (46879.599 us; speedup 1.0000x reference)
//
#include <hip/hip_runtime.h>

// RNNModel: B=64, T=512, I=256, H=1024, L=4 + FC(H->1).
// Round 3: single persistent kernel for the whole recurrence.
//   - 4 independent batch-groups (16 batches), 64 wgs each (16 features/wg).
//   - per-step sync inside a group via per-wg monotonic flag counters
//     (release store after h write; 64-lane coalesced acquire-poll).
//   - wg = 4 waves, K-split 4x256; W_ih/W_hh fragments held in VGPRs;
//     cross-wave reduce in LDS; ih-MFMAs issued BEFORE the poll.
//   - layer 0 reads x fp32 directly (in-register cvt) -> no x16 buffer.
// Workspace ~142.5 MB (< 148 MB proven safe in round 1).

typedef _Float16 f16;
typedef _Float16 f16x8 __attribute__((ext_vector_type(8)));
typedef float    f32x4 __attribute__((ext_vector_type(4)));

#define BB 64
#define TT 512
#define II 256
#define HH 1024

// ---------------- fp32 -> fp16 convert (vectorized, grid-stride) -------------
__global__ __launch_bounds__(256) void cvt_kernel(const float* __restrict__ in,
                                                  f16* __restrict__ out, int n4) {
  int stride = gridDim.x * blockDim.x;
  for (int i = blockIdx.x * blockDim.x + threadIdx.x; i < n4; i += stride) {
    float4 v = reinterpret_cast<const float4*>(in)[i];
    f16 h0 = (f16)v.x, h1 = (f16)v.y, h2 = (f16)v.z, h3 = (f16)v.w;
    _Float16 __attribute__((ext_vector_type(4))) h = { h0, h1, h2, h3 };
    reinterpret_cast<decltype(h)*>(out)[i] = h;
  }
}

__global__ __launch_bounds__(256) void bsum_kernel(const float* __restrict__ a,
                                                   const float* __restrict__ b,
                                                   float* __restrict__ o) {
  int i = blockIdx.x * blockDim.x + threadIdx.x;
  if (i < HH) o[i] = a[i] + b[i];
}

__global__ __launch_bounds__(256) void zero_kernel(unsigned int* __restrict__ p, int n) {
  int i = blockIdx.x * blockDim.x + threadIdx.x;
  if (i < n) p[i] = 0u;
}

// ---------------- persistent recurrence kernel -------------------------------
// grid = 256 wgs x 256 thr. wg (bg,fg): bg=wg>>6 batch-group, fg=wg&63 ->
// features [fg*16, fg*16+16). Waves 0..3 K-split (256 each). Flags[bg][fg] =
// number of completed global steps s = l*512+t (+1).
// MFMA 16x16x32_f16 layouts: A: lane=(m=l15, k=quad*8+j); B: lane=(k=quad*8+j,
// n=l15) i.e. 16B of W row n; C/D: lane=(row=quad*4+i, col=l15).
__global__ __launch_bounds__(256, 1) void rnn_persist(
    const float* __restrict__ x,   // [B][T][II] fp32
    f16* __restrict__ hsA,         // layers 1,3 output
    f16* __restrict__ hsB,         // layers 0,2 output
    const f16* __restrict__ wih0, const f16* __restrict__ whh0, const float* __restrict__ bs0,
    const f16* __restrict__ wih1, const f16* __restrict__ whh1, const float* __restrict__ bs1,
    const f16* __restrict__ wih2, const f16* __restrict__ whh2, const float* __restrict__ bs2,
    const f16* __restrict__ wih3, const f16* __restrict__ whh3, const float* __restrict__ bs3,
    unsigned int* __restrict__ flags) {
  const int wg = blockIdx.x;
  const int bg = wg >> 6, fg = wg & 63;
  const int wave = threadIdx.x >> 6, lane = threadIdx.x & 63;
  const int l15 = lane & 15, quad = lane >> 4;
  const int b0 = bg * 16, r0 = fg * 16;

  __shared__ f32x4 red[3 * 64];

  const f16* wih_t[4] = { wih0, wih1, wih2, wih3 };
  const f16* whh_t[4] = { whh0, whh1, whh2, whh3 };
  const float* bs_t[4] = { bs0, bs1, bs2, bs3 };
  unsigned int* myflags = flags + bg * 64;

  for (int l = 0; l < 4; ++l) {
    const f16* in_seq = (l & 1) ? hsB : hsA;  // l1<-hsB, l2<-hsA, l3<-hsB
    f16* out_seq = (l & 1) ? hsA : hsB;       // l0->hsB, l1->hsA, l2->hsB, l3->hsA
    const float bv = bs_t[l][r0 + l15];

    // ---- load weight fragments into VGPRs (wave w owns K in [w*256,w*256+256))
    f16x8 whhF[8];
    {
      const f16* wp = whh_t[l] + (size_t)(r0 + l15) * HH + wave * 256 + quad * 8;
#pragma unroll
      for (int f = 0; f < 8; ++f) whhF[f] = *reinterpret_cast<const f16x8*>(wp + f * 32);
    }
    f16x8 wihF[8];
    if (l == 0) {
      const f16* q = wih_t[0] + (size_t)(r0 + l15) * II + wave * 64 + quad * 8;
      wihF[0] = *reinterpret_cast<const f16x8*>(q);
      wihF[1] = *reinterpret_cast<const f16x8*>(q + 32);
    } else {
      const f16* q = wih_t[l] + (size_t)(r0 + l15) * HH + wave * 256 + quad * 8;
#pragma unroll
      for (int f = 0; f < 8; ++f) wihF[f] = *reinterpret_cast<const f16x8*>(q + f * 32);
    }

    for (int t = 0; t < TT; ++t) {
      const int s = l * TT + t;
      f32x4 c = {};
      if (wave == 0) { c[0] = bv; c[1] = bv; c[2] = bv; c[3] = bv; }

      // ---- input projection (independent of this step's flags) ----
      if (l == 0) {
        const float* xp = x + ((size_t)(b0 + l15) * TT + t) * II + wave * 64 + quad * 8;
#pragma unroll
        for (int f = 0; f < 2; ++f) {
          float4 u0 = *reinterpret_cast<const float4*>(xp + f * 32);
          float4 u1 = *reinterpret_cast<const float4*>(xp + f * 32 + 4);
          f16x8 a = { (f16)u0.x, (f16)u0.y, (f16)u0.z, (f16)u0.w,
                      (f16)u1.x, (f16)u1.y, (f16)u1.z, (f16)u1.w };
          c = __builtin_amdgcn_mfma_f32_16x16x32_f16(a, wihF[f], c, 0, 0, 0);
        }
      } else {
        const f16* ip = in_seq + ((size_t)(b0 + l15) * TT + t) * HH + wave * 256 + quad * 8;
#pragma unroll
        for (int f = 0; f < 8; ++f) {
          f16x8 a = *reinterpret_cast<const f16x8*>(ip + f * 32);
          c = __builtin_amdgcn_mfma_f32_16x16x32_f16(a, wihF[f], c, 0, 0, 0);
        }
      }

      // ---- wait for h_{t-1}, then recurrence MFMAs ----
      if (t > 0) {
        const unsigned int target = (unsigned int)s;
        for (;;) {
          unsigned int v = __hip_atomic_load(myflags + lane, __ATOMIC_ACQUIRE,
                                             __HIP_MEMORY_SCOPE_AGENT);
          if (__all((int)(v >= target))) break;
        }
        const f16* hp = out_seq + ((size_t)(b0 + l15) * TT + (t - 1)) * HH + wave * 256 + quad * 8;
#pragma unroll
        for (int f = 0; f < 8; ++f) {
          f16x8 a = *reinterpret_cast<const f16x8*>(hp + f * 32);
          c = __builtin_amdgcn_mfma_f32_16x16x32_f16(a, whhF[f], c, 0, 0, 0);
        }
      }

      // ---- cross-wave reduce, tanh, store, flag ----
      if (wave != 0) red[(wave - 1) * 64 + lane] = c;
      __syncthreads();
      if (wave == 0) {
#pragma unroll
        for (int w = 0; w < 3; ++w) c += red[w * 64 + lane];
        f16 hv[4];
#pragma unroll
        for (int i = 0; i < 4; ++i) {
          float e = __expf(2.0f * c[i]);          // tanh(x)=1-2/(e^{2x}+1)
          hv[i] = (f16)(1.0f - 2.0f / (e + 1.0f));
        }
#pragma unroll
        for (int i = 0; i < 4; ++i)
          out_seq[((size_t)(b0 + quad * 4 + i) * TT + t) * HH + r0 + l15] = hv[i];
        __threadfence();
        if (threadIdx.x == 0)
          __hip_atomic_store(myflags + fg, (unsigned int)(s + 1), __ATOMIC_RELEASE,
                             __HIP_MEMORY_SCOPE_AGENT);
      }
      __syncthreads();  // protects LDS `red` WAR at poll-skipped steps (t==0)
    }
  }
}

// ---------------- final FC: out[m] = hs[m][:] . fc_w + fc_b ------------------
__global__ __launch_bounds__(256) void fc_kernel(const f16* __restrict__ hs,
                                                 const float* __restrict__ fcw,
                                                 const float* __restrict__ fcb,
                                                 float* __restrict__ out) {
  const int lane = threadIdx.x & 63;
  const int m = blockIdx.x * 4 + (threadIdx.x >> 6);
  const f16* hp = hs + (size_t)m * HH;
  f16x8 v1 = *reinterpret_cast<const f16x8*>(hp + lane * 8);
  f16x8 v2 = *reinterpret_cast<const f16x8*>(hp + 512 + lane * 8);
  float acc = 0.f;
#pragma unroll
  for (int j = 0; j < 8; ++j) {
    acc += (float)v1[j] * fcw[lane * 8 + j];
    acc += (float)v2[j] * fcw[512 + lane * 8 + j];
  }
#pragma unroll
  for (int off = 32; off > 0; off >>= 1) acc += __shfl_down(acc, off, 64);
  if (lane == 0) out[m] = acc + fcb[0];
}

extern "C" void kernel_launch(void* const* d_in, const int* in_sizes, int n_in,
                              void* d_out, int out_size, void* d_ws, size_t ws_size,
                              hipStream_t stream) {
  const float* x   = (const float*)d_in[0];
  const float* fcw = (const float*)d_in[17];
  const float* fcb = (const float*)d_in[18];

  char* ws = (char*)d_ws;
  size_t off = 0;
  auto alloc = [&](size_t bytes) -> void* {
    void* p = ws + off;
    off += (bytes + 255) & ~(size_t)255;
    return p;
  };
  f16* hsA = (f16*)alloc((size_t)BB * TT * HH * 2);  // 64 MB
  f16* hsB = (f16*)alloc((size_t)BB * TT * HH * 2);  // 64 MB
  f16* w16ih[4];
  f16* w16hh[4];
  float* bsum[4];
  for (int l = 0; l < 4; ++l) {
    int din = (l == 0) ? II : HH;
    w16ih[l] = (f16*)alloc((size_t)HH * din * 2);
    w16hh[l] = (f16*)alloc((size_t)HH * HH * 2);
    bsum[l]  = (float*)alloc(HH * 4);
  }
  unsigned int* flags = (unsigned int*)alloc(256 * 4);  // total ~142.6 MB

  for (int l = 0; l < 4; ++l) {
    int din = (l == 0) ? II : HH;
    cvt_kernel<<<512, 256, 0, stream>>>((const float*)d_in[1 + 4 * l], w16ih[l],
                                        HH * din / 4);
    cvt_kernel<<<512, 256, 0, stream>>>((const float*)d_in[2 + 4 * l], w16hh[l],
                                        HH * HH / 4);
    bsum_kernel<<<4, 256, 0, stream>>>((const float*)d_in[3 + 4 * l],
                                       (const float*)d_in[4 + 4 * l], bsum[l]);
  }
  zero_kernel<<<1, 256, 0, stream>>>(flags, 256);

  rnn_persist<<<256, 256, 0, stream>>>(
      x, hsA, hsB,
      w16ih[0], w16hh[0], bsum[0],
      w16ih[1], w16hh[1], bsum[1],
      w16ih[2], w16hh[2], bsum[2],
      w16ih[3], w16hh[3], bsum[3],
      flags);

  fc_kernel<<<BB * TT / 4, 256, 0, stream>>>(hsA, fcw, fcb, (float*)d_out);
}

// Round 4
// 22417.987 us; speedup vs baseline: 2.0912x; 2.0912x over previous
//
#include <hip/hip_runtime.h>

// RNNModel: B=64, T=512, I=256, H=1024, L=4 + FC(H->1).
// Round 4: persistent kernel, cache-maintenance-free sync.
//   Round-3 failure: agent-scope acquire polls emitted buffer_inv (whole-L2
//   invalidate) and release/threadfence emitted buffer_wbl2 per step -> 2 GB
//   HBM refetch, 23 us/step. Fix: ALL h/flag traffic uses RELAXED+SYSTEM
//   atomics -> sc0 sc1 bypass accesses served by the Infinity Cache, no
//   cache-wide ops. Release ordering via inline s_waitcnt vmcnt(0) +
//   __syncthreads before the flag store.
//   Layout: 4 batch-groups x 16 wgs (64 features/wg, 4 waves K-split 256).
//   Weights streamed from L2 (read-only, cached); h repacked via LDS so each
//   thread does one aligned 8B bypass store.

typedef _Float16 f16;
typedef _Float16 f16x8 __attribute__((ext_vector_type(8)));
typedef float    f32x4 __attribute__((ext_vector_type(4)));

#define BB 64
#define TT 512
#define II 256
#define HH 1024

union U16 { unsigned long long u[2]; f16x8 v; };

#define SYS_LOAD_U64(p) __hip_atomic_load((const unsigned long long*)(p), \
    __ATOMIC_RELAXED, __HIP_MEMORY_SCOPE_SYSTEM)
#define SYS_STORE_U64(p, x) __hip_atomic_store((unsigned long long*)(p), (x), \
    __ATOMIC_RELAXED, __HIP_MEMORY_SCOPE_SYSTEM)

#define MFMA(a, b, c) __builtin_amdgcn_mfma_f32_16x16x32_f16((a), (b), (c), 0, 0, 0)

// ---------------- fp32 -> fp16 convert (vectorized, grid-stride) -------------
__global__ __launch_bounds__(256) void cvt_kernel(const float* __restrict__ in,
                                                  f16* __restrict__ out, int n4) {
  int stride = gridDim.x * blockDim.x;
  for (int i = blockIdx.x * blockDim.x + threadIdx.x; i < n4; i += stride) {
    float4 v = reinterpret_cast<const float4*>(in)[i];
    _Float16 __attribute__((ext_vector_type(4))) h = { (f16)v.x, (f16)v.y,
                                                       (f16)v.z, (f16)v.w };
    reinterpret_cast<decltype(h)*>(out)[i] = h;
  }
}

__global__ __launch_bounds__(256) void bsum_kernel(const float* __restrict__ a,
                                                   const float* __restrict__ b,
                                                   float* __restrict__ o) {
  int i = blockIdx.x * blockDim.x + threadIdx.x;
  if (i < HH) o[i] = a[i] + b[i];
}

__global__ __launch_bounds__(256) void zero_kernel(unsigned int* __restrict__ p, int n) {
  int i = blockIdx.x * blockDim.x + threadIdx.x;
  if (i < n) p[i] = 0u;
}

// ---------------- persistent recurrence kernel -------------------------------
// grid = 64 wgs x 256 thr. wg -> (bg = wg>>4 batch-group of 16, fg = wg&15 ->
// features [fg*64, fg*64+64)). Wave w K-splits [w*256, w*256+256) and owns
// output feature tile w (cols fg*64 + w*16 ..+16) after the LDS reduce.
// flags[bg*16+fg] = #completed steps s = l*512+t (+1), SYSTEM-relaxed.
// MFMA 16x16x32_f16: A lane=(m=l15, k=quad*8+j); B lane=(k=quad*8+j, n=l15)
// = 16B of W row n; C/D lane=(row=quad*4+i, col=l15).
__global__ __launch_bounds__(256, 1) void rnn_persist(
    const float* __restrict__ x,   // [B][T][II] fp32
    f16* __restrict__ hsA,         // layers 1,3 output
    f16* __restrict__ hsB,         // layers 0,2 output
    const f16* __restrict__ wih0, const f16* __restrict__ whh0, const float* __restrict__ bs0,
    const f16* __restrict__ wih1, const f16* __restrict__ whh1, const float* __restrict__ bs1,
    const f16* __restrict__ wih2, const f16* __restrict__ whh2, const float* __restrict__ bs2,
    const f16* __restrict__ wih3, const f16* __restrict__ whh3, const float* __restrict__ bs3,
    unsigned int* __restrict__ flags) {
  const int wg = blockIdx.x;
  const int bg = wg >> 4, fg = wg & 15;
  const int wave = threadIdx.x >> 6, lane = threadIdx.x & 63;
  const int l15 = lane & 15, quad = lane >> 4;
  const int b0 = bg * 16;
  const int r0 = fg * 64;

  __shared__ f32x4 red[16 * 64];                 // [srcwave][ntile][lane], 16 KB
  __shared__ __align__(16) f16 hstage[16 * 64];  // [row=batch][col=feature], 2 KB

  const f16* wih_t[4] = { wih0, wih1, wih2, wih3 };
  const f16* whh_t[4] = { whh0, whh1, whh2, whh3 };
  const float* bs_t[4] = { bs0, bs1, bs2, bs3 };
  unsigned int* myflags = flags + bg * 16;

  const int srow = threadIdx.x >> 4;        // 0..15  (batch row for h store)
  const int scol = (threadIdx.x & 15) * 4;  // 0..60  (feature col group)

  for (int l = 0; l < 4; ++l) {
    const f16* in_seq = (l & 1) ? hsB : hsA;  // l1<-hsB(l0), l2<-hsA(l1), l3<-hsB(l2)
    f16* out_seq = (l & 1) ? hsA : hsB;       // l0->hsB, l1->hsA, l2->hsB, l3->hsA
    const f16* wihL = wih_t[l];
    const f16* whhL = whh_t[l];
    const float bv = bs_t[l][r0 + wave * 16 + l15];

    for (int t = 0; t < TT; ++t) {
      const int s = l * TT + t;
      f32x4 c0 = {}, c1 = {}, c2 = {}, c3 = {};

      // ---- input projection (independent of this step's flags; pre-poll) ----
      if (l == 0) {
        const float* xp = x + ((size_t)(b0 + l15) * TT + t) * II + wave * 64 + quad * 8;
        const f16* wb = wihL + (size_t)(r0 + l15) * II + wave * 64 + quad * 8;
#pragma unroll
        for (int kf = 0; kf < 2; ++kf) {
          float4 u0 = *reinterpret_cast<const float4*>(xp + kf * 32);
          float4 u1 = *reinterpret_cast<const float4*>(xp + kf * 32 + 4);
          f16x8 a = { (f16)u0.x, (f16)u0.y, (f16)u0.z, (f16)u0.w,
                      (f16)u1.x, (f16)u1.y, (f16)u1.z, (f16)u1.w };
          c0 = MFMA(a, *reinterpret_cast<const f16x8*>(wb + kf * 32), c0);
          c1 = MFMA(a, *reinterpret_cast<const f16x8*>(wb + 16 * II + kf * 32), c1);
          c2 = MFMA(a, *reinterpret_cast<const f16x8*>(wb + 32 * II + kf * 32), c2);
          c3 = MFMA(a, *reinterpret_cast<const f16x8*>(wb + 48 * II + kf * 32), c3);
        }
      } else {
        const char* ip = (const char*)(in_seq + ((size_t)(b0 + l15) * TT + t) * HH +
                                       wave * 256 + quad * 8);
        const f16* wb = wihL + (size_t)(r0 + l15) * HH + wave * 256 + quad * 8;
#pragma unroll
        for (int kf = 0; kf < 8; ++kf) {
          U16 av;
          av.u[0] = SYS_LOAD_U64(ip + kf * 64);
          av.u[1] = SYS_LOAD_U64(ip + kf * 64 + 8);
          c0 = MFMA(av.v, *reinterpret_cast<const f16x8*>(wb + kf * 32), c0);
          c1 = MFMA(av.v, *reinterpret_cast<const f16x8*>(wb + 16 * HH + kf * 32), c1);
          c2 = MFMA(av.v, *reinterpret_cast<const f16x8*>(wb + 32 * HH + kf * 32), c2);
          c3 = MFMA(av.v, *reinterpret_cast<const f16x8*>(wb + 48 * HH + kf * 32), c3);
        }
      }

      // ---- wait for h_{t-1} (bypass poll, no cache maintenance), then W_hh ----
      if (t > 0) {
        const unsigned int target = (unsigned int)s;
        for (;;) {
          unsigned int v = __hip_atomic_load(myflags + (lane & 15), __ATOMIC_RELAXED,
                                             __HIP_MEMORY_SCOPE_SYSTEM);
          if (__all((int)(v >= target))) break;
        }
        const char* hp = (const char*)(out_seq + ((size_t)(b0 + l15) * TT + (t - 1)) * HH +
                                       wave * 256 + quad * 8);
        const f16* wb = whhL + (size_t)(r0 + l15) * HH + wave * 256 + quad * 8;
#pragma unroll
        for (int kf = 0; kf < 8; ++kf) {
          U16 av;
          av.u[0] = SYS_LOAD_U64(hp + kf * 64);
          av.u[1] = SYS_LOAD_U64(hp + kf * 64 + 8);
          c0 = MFMA(av.v, *reinterpret_cast<const f16x8*>(wb + kf * 32), c0);
          c1 = MFMA(av.v, *reinterpret_cast<const f16x8*>(wb + 16 * HH + kf * 32), c1);
          c2 = MFMA(av.v, *reinterpret_cast<const f16x8*>(wb + 32 * HH + kf * 32), c2);
          c3 = MFMA(av.v, *reinterpret_cast<const f16x8*>(wb + 48 * HH + kf * 32), c3);
        }
      }

      // ---- cross-wave K-reduce: wave w takes ntile w ----
      red[(wave * 4 + 0) * 64 + lane] = c0;
      red[(wave * 4 + 1) * 64 + lane] = c1;
      red[(wave * 4 + 2) * 64 + lane] = c2;
      red[(wave * 4 + 3) * 64 + lane] = c3;
      __syncthreads();
      f32x4 tot = red[(0 * 4 + wave) * 64 + lane] + red[(1 * 4 + wave) * 64 + lane] +
                  red[(2 * 4 + wave) * 64 + lane] + red[(3 * 4 + wave) * 64 + lane];

      // ---- bias + tanh, repack into [batch][feature] LDS tile ----
#pragma unroll
      for (int i = 0; i < 4; ++i) {
        float e = __expf(2.0f * (tot[i] + bv));   // tanh(x) = 1 - 2/(e^{2x}+1)
        hstage[(quad * 4 + i) * 64 + wave * 16 + l15] = (f16)(1.0f - 2.0f / (e + 1.0f));
      }
      __syncthreads();

      // ---- one aligned 8B bypass store per thread + release flag ----
      unsigned long long hw =
          *reinterpret_cast<const unsigned long long*>(&hstage[srow * 64 + scol]);
      SYS_STORE_U64(out_seq + ((size_t)(b0 + srow) * TT + t) * HH + r0 + scol, hw);
      asm volatile("s_waitcnt vmcnt(0)" ::: "memory");  // stores acked at coherence pt
      __syncthreads();                                  // all waves' stores done
      if (threadIdx.x == 0)
        __hip_atomic_store(myflags + fg, (unsigned int)(s + 1), __ATOMIC_RELAXED,
                           __HIP_MEMORY_SCOPE_SYSTEM);
    }
  }
}

// ---------------- final FC: out[m] = hs[m][:] . fc_w + fc_b ------------------
__global__ __launch_bounds__(256) void fc_kernel(const f16* __restrict__ hs,
                                                 const float* __restrict__ fcw,
                                                 const float* __restrict__ fcb,
                                                 float* __restrict__ out) {
  const int lane = threadIdx.x & 63;
  const int m = blockIdx.x * 4 + (threadIdx.x >> 6);
  const f16* hp = hs + (size_t)m * HH;
  f16x8 v1 = *reinterpret_cast<const f16x8*>(hp + lane * 8);
  f16x8 v2 = *reinterpret_cast<const f16x8*>(hp + 512 + lane * 8);
  float acc = 0.f;
#pragma unroll
  for (int j = 0; j < 8; ++j) {
    acc += (float)v1[j] * fcw[lane * 8 + j];
    acc += (float)v2[j] * fcw[512 + lane * 8 + j];
  }
#pragma unroll
  for (int off = 32; off > 0; off >>= 1) acc += __shfl_down(acc, off, 64);
  if (lane == 0) out[m] = acc + fcb[0];
}

extern "C" void kernel_launch(void* const* d_in, const int* in_sizes, int n_in,
                              void* d_out, int out_size, void* d_ws, size_t ws_size,
                              hipStream_t stream) {
  const float* x   = (const float*)d_in[0];
  const float* fcw = (const float*)d_in[17];
  const float* fcb = (const float*)d_in[18];

  char* ws = (char*)d_ws;
  size_t off = 0;
  auto alloc = [&](size_t bytes) -> void* {
    void* p = ws + off;
    off += (bytes + 255) & ~(size_t)255;
    return p;
  };
  f16* hsA = (f16*)alloc((size_t)BB * TT * HH * 2);  // 64 MB
  f16* hsB = (f16*)alloc((size_t)BB * TT * HH * 2);  // 64 MB
  f16* w16ih[4];
  f16* w16hh[4];
  float* bsum[4];
  for (int l = 0; l < 4; ++l) {
    int din = (l == 0) ? II : HH;
    w16ih[l] = (f16*)alloc((size_t)HH * din * 2);
    w16hh[l] = (f16*)alloc((size_t)HH * HH * 2);
    bsum[l]  = (float*)alloc(HH * 4);
  }
  unsigned int* flags = (unsigned int*)alloc(256 * 4);  // total ~142.6 MB

  for (int l = 0; l < 4; ++l) {
    int din = (l == 0) ? II : HH;
    cvt_kernel<<<512, 256, 0, stream>>>((const float*)d_in[1 + 4 * l], w16ih[l],
                                        HH * din / 4);
    cvt_kernel<<<512, 256, 0, stream>>>((const float*)d_in[2 + 4 * l], w16hh[l],
                                        HH * HH / 4);
    bsum_kernel<<<4, 256, 0, stream>>>((const float*)d_in[3 + 4 * l],
                                       (const float*)d_in[4 + 4 * l], bsum[l]);
  }
  zero_kernel<<<1, 256, 0, stream>>>(flags, 256);

  rnn_persist<<<64, 256, 0, stream>>>(
      x, hsA, hsB,
      w16ih[0], w16hh[0], bsum[0],
      w16ih[1], w16hh[1], bsum[1],
      w16ih[2], w16hh[2], bsum[2],
      w16ih[3], w16hh[3], bsum[3],
      flags);

  fc_kernel<<<BB * TT / 4, 256, 0, stream>>>(hsA, fcw, fcb, (float*)d_out);
}

// Round 5
// 3286.600 us; speedup vs baseline: 14.2639x; 6.8210x over previous
//
#include <hip/hip_runtime.h>

// RNNModel: B=64, T=512, I=256, H=1024, L=4 + FC(H->1).
// Round 5: layer-pipelined persistent kernel.
//   - 16 pairs (layer l, batch-group bg) x 16 wgs (64 features) = 256 wgs,
//     1 wg/CU, 4 waves/wg (1 wave/SIMD -> full 512-VGPR budget per wave).
//   - W_ih and W_hh slices fully register-resident (256 VGPRs of weights):
//     zero per-step weight traffic (round-4 streamed 256 KB/step through L1).
//   - Layers run CONCURRENTLY, pipelined over t via ring buffers (RING=64
//     slots per layer) + flag-based producer/consumer sync. Serial depth
//     2048 -> ~515 steps. Deadlock-free: phi(l,t)=4t+l strictly decreases
//     along every dependency (own t-1, producer t, consumer t-RING).
//   - All h/flag traffic: RELAXED+SYSTEM bypass (sc0 sc1, IC-served, no
//     cache-maintenance ops -- round-3 lesson). Release = s_waitcnt vmcnt(0)
//     + __syncthreads before flag store (round-4 proven).
//   - FC fused into layer-3 wgs (atomicAdd fp32, out init'd to fc_b).
// Workspace ~47 MB.

typedef _Float16 f16;
typedef _Float16 f16x8 __attribute__((ext_vector_type(8)));
typedef float    f32x4 __attribute__((ext_vector_type(4)));

#define BB 64
#define TT 512
#define II 256
#define HH 1024
#define RING 64

union U16u { unsigned long long u[2]; f16x8 v; };

#define SYS_LOAD_U64(p) __hip_atomic_load((const unsigned long long*)(p), \
    __ATOMIC_RELAXED, __HIP_MEMORY_SCOPE_SYSTEM)
#define SYS_STORE_U64(p, x) __hip_atomic_store((unsigned long long*)(p), (x), \
    __ATOMIC_RELAXED, __HIP_MEMORY_SCOPE_SYSTEM)

#define MFMA(a, b, c) __builtin_amdgcn_mfma_f32_16x16x32_f16((a), (b), (c), 0, 0, 0)

// ---------------- small prep kernels ----------------------------------------
__global__ __launch_bounds__(256) void cvt_kernel(const float* __restrict__ in,
                                                  f16* __restrict__ out, int n4) {
  int stride = gridDim.x * blockDim.x;
  for (int i = blockIdx.x * blockDim.x + threadIdx.x; i < n4; i += stride) {
    float4 v = reinterpret_cast<const float4*>(in)[i];
    _Float16 __attribute__((ext_vector_type(4))) h = { (f16)v.x, (f16)v.y,
                                                       (f16)v.z, (f16)v.w };
    reinterpret_cast<decltype(h)*>(out)[i] = h;
  }
}

__global__ __launch_bounds__(256) void bsum_kernel(const float* __restrict__ a,
                                                   const float* __restrict__ b,
                                                   float* __restrict__ o) {
  int i = blockIdx.x * blockDim.x + threadIdx.x;
  if (i < HH) o[i] = a[i] + b[i];
}

__global__ __launch_bounds__(256) void zero_kernel(int* __restrict__ p, int n) {
  int i = blockIdx.x * blockDim.x + threadIdx.x;
  if (i < n) p[i] = 0;
}

__global__ __launch_bounds__(256) void initout_kernel(float* __restrict__ out,
                                                      const float* __restrict__ fcb,
                                                      int n) {
  int i = blockIdx.x * blockDim.x + threadIdx.x;
  if (i < n) out[i] = fcb[0];
}

// ---------------- layer-pipelined persistent kernel --------------------------
// blockIdx: p = blk&15 (pair: l=p>>2, bg=p&3), wgp = blk>>4 (features
// [wgp*64, wgp*64+64)). Wave w K-splits [w*256, w*256+256) and owns output
// ntile w (cols wgp*64 + w*16..+16) after the LDS reduce.
// flags[p*16+wgp] = #completed steps t (+1) of pair p's wg wgp.
// Rings: ring_l[b][slot][feat], slot = t & 63.
// MFMA 16x16x32_f16: A lane=(m=l15, k=quad*8+j); B lane=(k=quad*8+j, n=l15)
// = 16B of W row n; C/D lane=(row=quad*4+i, col=l15).
__global__ __launch_bounds__(256, 1) void rnn_persist(
    const float* __restrict__ x,
    f16* __restrict__ ring0, f16* __restrict__ ring1,
    f16* __restrict__ ring2, f16* __restrict__ ring3,
    const f16* __restrict__ wih0, const f16* __restrict__ wih1,
    const f16* __restrict__ wih2, const f16* __restrict__ wih3,
    const f16* __restrict__ whh0, const f16* __restrict__ whh1,
    const f16* __restrict__ whh2, const f16* __restrict__ whh3,
    const float* __restrict__ bs0, const float* __restrict__ bs1,
    const float* __restrict__ bs2, const float* __restrict__ bs3,
    const float* __restrict__ fcw, float* __restrict__ out,
    int* __restrict__ flags) {
  const int p = blockIdx.x & 15, wgp = blockIdx.x >> 4;
  const int l = p >> 2, bg = p & 3;
  const int wave = threadIdx.x >> 6, lane = threadIdx.x & 63;
  const int l15 = lane & 15, quad = lane >> 4;
  const int b0 = bg * 16, r0 = wgp * 64;
  const int srow = threadIdx.x >> 4;        // batch row for h store
  const int scol = (threadIdx.x & 15) * 4;  // feature col group

  __shared__ f32x4 red[16 * 64];                 // 16 KB
  __shared__ __align__(16) f16 hstage[16 * 64];  // 2 KB

  f16* rings[4] = { ring0, ring1, ring2, ring3 };
  const f16* wih_t[4] = { wih0, wih1, wih2, wih3 };
  const f16* whh_t[4] = { whh0, whh1, whh2, whh3 };
  const float* bs_t[4] = { bs0, bs1, bs2, bs3 };

  const f16* in_ring = (l > 0) ? rings[l - 1] : (const f16*)0;
  f16* out_ring = rings[l];
  const float bv = bs_t[l][r0 + wave * 16 + l15];

  // ---- register-resident weight fragments (1 wave/SIMD -> 512 VGPRs ok) ----
  f16x8 whhF[4][8];
  {
    const f16* q = whh_t[l] + (size_t)(r0 + l15) * HH + wave * 256 + quad * 8;
#pragma unroll
    for (int j = 0; j < 4; ++j)
#pragma unroll
      for (int f = 0; f < 8; ++f)
        whhF[j][f] = *reinterpret_cast<const f16x8*>(q + (size_t)j * 16 * HH + f * 32);
  }
  f16x8 wihF[4][8];
  if (l == 0) {
    const f16* q = wih_t[0] + (size_t)(r0 + l15) * II + wave * 64 + quad * 8;
#pragma unroll
    for (int j = 0; j < 4; ++j)
#pragma unroll
      for (int f = 0; f < 2; ++f)
        wihF[j][f] = *reinterpret_cast<const f16x8*>(q + (size_t)j * 16 * II + f * 32);
  } else {
    const f16* q = wih_t[l] + (size_t)(r0 + l15) * HH + wave * 256 + quad * 8;
#pragma unroll
    for (int j = 0; j < 4; ++j)
#pragma unroll
      for (int f = 0; f < 8; ++f)
        wihF[j][f] = *reinterpret_cast<const f16x8*>(q + (size_t)j * 16 * HH + f * 32);
  }
  float4 fcwv = { 0.f, 0.f, 0.f, 0.f };
  if (l == 3) fcwv = *reinterpret_cast<const float4*>(fcw + r0 + (threadIdx.x & 15) * 4);

  // ---- poll setup: lanes 0-15 own pair (tgt t), 16-31 producer (tgt t+1),
  //      32-47 consumer backpressure (tgt t-RING+1) ----
  const int which = lane >> 4;
  int psel = p + ((which == 1) ? -4 : (which == 2) ? 4 : 0);
  psel = psel < 0 ? 0 : (psel > 15 ? 15 : psel);
  const int* fptr = flags + psel * 16 + l15;
  unsigned long long need = 0xFFFFull;
  if (l > 0) need |= 0xFFFF0000ull;
  if (l < 3) need |= 0xFFFF00000000ull;
  int* myflag = flags + p * 16 + wgp;

  for (int t = 0; t < TT; ++t) {
    const int slot = t & (RING - 1);
    f32x4 c0 = {}, c1 = {}, c2 = {}, c3 = {};

    // ---- layer 0: x is always ready -> do ih MFMAs before the poll ----
    if (l == 0) {
      const float* xp = x + ((size_t)(b0 + l15) * TT + t) * II + wave * 64 + quad * 8;
#pragma unroll
      for (int f = 0; f < 2; ++f) {
        float4 u0 = *reinterpret_cast<const float4*>(xp + f * 32);
        float4 u1 = *reinterpret_cast<const float4*>(xp + f * 32 + 4);
        f16x8 a = { (f16)u0.x, (f16)u0.y, (f16)u0.z, (f16)u0.w,
                    (f16)u1.x, (f16)u1.y, (f16)u1.z, (f16)u1.w };
        c0 = MFMA(a, wihF[0][f], c0);
        c1 = MFMA(a, wihF[1][f], c1);
        c2 = MFMA(a, wihF[2][f], c2);
        c3 = MFMA(a, wihF[3][f], c3);
      }
    }

    // ---- combined poll: h_{t-1} ready, in[t] ready, ring slot free ----
    {
      const int tgt = (which == 0) ? t : (which == 1) ? t + 1 : t - RING + 1;
      for (;;) {
        int v = __hip_atomic_load(fptr, __ATOMIC_RELAXED, __HIP_MEMORY_SCOPE_SYSTEM);
        if ((__ballot(v >= tgt) & need) == need) break;
      }
    }

    // ---- ih from producer ring (bypass loads) ----
    if (l > 0) {
      const char* ip = (const char*)(in_ring + ((size_t)(b0 + l15) * RING + slot) * HH +
                                     wave * 256 + quad * 8);
#pragma unroll
      for (int f = 0; f < 8; ++f) {
        U16u av;
        av.u[0] = SYS_LOAD_U64(ip + f * 64);
        av.u[1] = SYS_LOAD_U64(ip + f * 64 + 8);
        c0 = MFMA(av.v, wihF[0][f], c0);
        c1 = MFMA(av.v, wihF[1][f], c1);
        c2 = MFMA(av.v, wihF[2][f], c2);
        c3 = MFMA(av.v, wihF[3][f], c3);
      }
    }

    // ---- hh from own ring slot t-1 ----
    if (t > 0) {
      const int slotp = (t - 1) & (RING - 1);
      const char* hp = (const char*)(out_ring + ((size_t)(b0 + l15) * RING + slotp) * HH +
                                     wave * 256 + quad * 8);
#pragma unroll
      for (int f = 0; f < 8; ++f) {
        U16u av;
        av.u[0] = SYS_LOAD_U64(hp + f * 64);
        av.u[1] = SYS_LOAD_U64(hp + f * 64 + 8);
        c0 = MFMA(av.v, whhF[0][f], c0);
        c1 = MFMA(av.v, whhF[1][f], c1);
        c2 = MFMA(av.v, whhF[2][f], c2);
        c3 = MFMA(av.v, whhF[3][f], c3);
      }
    }

    // ---- cross-wave K-reduce: wave w takes ntile w ----
    red[(wave * 4 + 0) * 64 + lane] = c0;
    red[(wave * 4 + 1) * 64 + lane] = c1;
    red[(wave * 4 + 2) * 64 + lane] = c2;
    red[(wave * 4 + 3) * 64 + lane] = c3;
    __syncthreads();
    f32x4 tot = red[(0 * 4 + wave) * 64 + lane] + red[(1 * 4 + wave) * 64 + lane] +
                red[(2 * 4 + wave) * 64 + lane] + red[(3 * 4 + wave) * 64 + lane];

    // ---- bias + tanh, repack to [batch][feature] ----
#pragma unroll
    for (int i = 0; i < 4; ++i) {
      float e = __expf(2.0f * (tot[i] + bv));   // tanh(x) = 1 - 2/(e^{2x}+1)
      hstage[(quad * 4 + i) * 64 + wave * 16 + l15] = (f16)(1.0f - 2.0f / (e + 1.0f));
    }
    __syncthreads();

    // ---- one aligned 8B bypass store per thread into own ring slot ----
    unsigned long long hw =
        *reinterpret_cast<const unsigned long long*>(&hstage[srow * 64 + scol]);
    SYS_STORE_U64(out_ring + ((size_t)(b0 + srow) * RING + slot) * HH + r0 + scol, hw);

    // ---- fused FC for layer 3 (partial dot from the same 8B register) ----
    if (l == 3) {
      union { unsigned long long u; f16 h[4]; } hu;
      hu.u = hw;
      float partial = (float)hu.h[0] * fcwv.x + (float)hu.h[1] * fcwv.y +
                      (float)hu.h[2] * fcwv.z + (float)hu.h[3] * fcwv.w;
      partial += __shfl_down(partial, 8, 16);
      partial += __shfl_down(partial, 4, 16);
      partial += __shfl_down(partial, 2, 16);
      partial += __shfl_down(partial, 1, 16);
      if ((threadIdx.x & 15) == 0)
        atomicAdd(out + (size_t)(b0 + srow) * TT + t, partial);
    }

    asm volatile("s_waitcnt vmcnt(0)" ::: "memory");  // stores/atomics acked
    __syncthreads();                                  // all waves done
    if (threadIdx.x == 0)
      __hip_atomic_store(myflag, t + 1, __ATOMIC_RELAXED, __HIP_MEMORY_SCOPE_SYSTEM);
  }
}

extern "C" void kernel_launch(void* const* d_in, const int* in_sizes, int n_in,
                              void* d_out, int out_size, void* d_ws, size_t ws_size,
                              hipStream_t stream) {
  const float* x   = (const float*)d_in[0];
  const float* fcw = (const float*)d_in[17];
  const float* fcb = (const float*)d_in[18];

  char* ws = (char*)d_ws;
  size_t off = 0;
  auto alloc = [&](size_t bytes) -> void* {
    void* p = ws + off;
    off += (bytes + 255) & ~(size_t)255;
    return p;
  };
  f16* ring[4];
  for (int l = 0; l < 4; ++l)
    ring[l] = (f16*)alloc((size_t)BB * RING * HH * 2);  // 8 MB each
  f16* w16ih[4];
  f16* w16hh[4];
  float* bsum[4];
  for (int l = 0; l < 4; ++l) {
    int din = (l == 0) ? II : HH;
    w16ih[l] = (f16*)alloc((size_t)HH * din * 2);
    w16hh[l] = (f16*)alloc((size_t)HH * HH * 2);
    bsum[l]  = (float*)alloc(HH * 4);
  }
  int* flags = (int*)alloc(256 * 4);  // total ~47 MB

  for (int l = 0; l < 4; ++l) {
    int din = (l == 0) ? II : HH;
    cvt_kernel<<<512, 256, 0, stream>>>((const float*)d_in[1 + 4 * l], w16ih[l],
                                        HH * din / 4);
    cvt_kernel<<<512, 256, 0, stream>>>((const float*)d_in[2 + 4 * l], w16hh[l],
                                        HH * HH / 4);
    bsum_kernel<<<4, 256, 0, stream>>>((const float*)d_in[3 + 4 * l],
                                       (const float*)d_in[4 + 4 * l], bsum[l]);
  }
  zero_kernel<<<1, 256, 0, stream>>>(flags, 256);
  initout_kernel<<<BB * TT / 256, 256, 0, stream>>>((float*)d_out, fcb, BB * TT);

  rnn_persist<<<256, 256, 0, stream>>>(
      x, ring[0], ring[1], ring[2], ring[3],
      w16ih[0], w16ih[1], w16ih[2], w16ih[3],
      w16hh[0], w16hh[1], w16hh[2], w16hh[3],
      bsum[0], bsum[1], bsum[2], bsum[3],
      fcw, (float*)d_out, flags);
}